// Round 4
// baseline (2603.400 us; speedup 1.0000x reference)
//
#include <hip/hip_runtime.h>
#include <stdint.h>

// RandomPropagate: 100 steps of jitter -> 3x3 maxpool -> coin mask -> goodness
// scale -> threshold commit, on a 2048x2048 f32 grid.
//
// Round 4: upper-bound-gated RNG. Key invariant: s = 0.9999+1e-4*u1 <= 1.0
// => t = fl(x*s) <= x => m = maxpool(t) <= M = maxpool(x); fmul/fsub_rn are
// monotone => if fl(fl(M*good)-x) <= THR the commit test cannot pass for ANY
// rng outcome. So:
//   phase 1: stage RAW x (no rng). all-zero tile -> write zeros, done.
//   phase 2: M = max9(x) from LDS; pre-test fl(M-x)>THR (good<1, skips the
//            good load); flag = fl(fl(M*good)-x)>THR. no flags -> copy, done.
//   phase 3: dilate flags onto staged cells (cells feeding a flagged px),
//            compact needed cells (x!=0) into an LDS worklist (atomicAdd) --
//            compaction keeps all 64 lanes busy, divergence can't eat sparsity.
//   phase 4: worklist cells draw jitter once, overwrite xs in place.
//   phase 5: flagged px: exact m, v=fl(m*good), exact test, coin draw, commit.
// Every consumed rng bit identical to reference (per-pixel counter streams;
// skipped draws are side-effect free). x ping-pongs d_out <-> d_ws (100 even
// steps -> result ends in d_out).
//
// PRNG: JAX threefry2x32, partitionable mode (bit-exact, absmax 0.0 R1-R3):
//   fold_in(key, i)       = tf2x32(key, (0, i))
//   split(F)[j]           = tf2x32(F,   (0, j))
//   random_bits32(key, p) = o0 ^ o1 of tf2x32(key, (0, p))
//   uniform01(bits)       = bitcast((bits>>9)|0x3f800000) - 1.0f
// All f32 math uses _rn intrinsics to forbid FMA contraction.

#define HH 2048
#define WW 2048
#define NPIX (HH * WW)
#define TS 64           // output tile side
#define PADW (TS + 2)   // 66, LDS row stride
#define NSTG (PADW * PADW)

// ---------- threefry2x32, exact JAX round structure ----------
__host__ __device__ __forceinline__ void tf2x32(uint32_t k0, uint32_t k1,
                                                uint32_t c0, uint32_t c1,
                                                uint32_t* o0, uint32_t* o1) {
  uint32_t ks2 = k0 ^ k1 ^ 0x1BD11BDAu;
  uint32_t x0 = c0 + k0, x1 = c1 + k1;
#define TFR(r) do { x0 += x1; x1 = (x1 << (r)) | (x1 >> (32 - (r))); x1 ^= x0; } while (0);
  TFR(13) TFR(15) TFR(26) TFR(6)
  x0 += k1; x1 += ks2 + 1u;
  TFR(17) TFR(29) TFR(16) TFR(24)
  x0 += ks2; x1 += k0 + 2u;
  TFR(13) TFR(15) TFR(26) TFR(6)
  x0 += k0; x1 += k1 + 3u;
  TFR(17) TFR(29) TFR(16) TFR(24)
  x0 += k1; x1 += ks2 + 4u;
  TFR(13) TFR(15) TFR(26) TFR(6)
  x0 += ks2; x1 += k0 + 5u;
#undef TFR
  *o0 = x0; *o1 = x1;
}

__device__ __forceinline__ float uniform01(uint32_t ka, uint32_t kb, uint32_t p) {
  uint32_t o0, o1;
  tf2x32(ka, kb, 0u, p, &o0, &o1);
  uint32_t bits = o0 ^ o1;  // partitionable 32-bit XOR fold
  return __uint_as_float((bits >> 9) | 0x3F800000u) - 1.0f;
}

// x0 = seed * habitat * goodness  (seed is exactly 0/1, so rounding is exact)
__global__ void k_init(const float* __restrict__ seed,
                       const float* __restrict__ hab,
                       const float* __restrict__ good,
                       float* __restrict__ x) {
  int p = blockIdx.x * blockDim.x + threadIdx.x;
  if (p >= NPIX) return;
  x[p] = __fmul_rn(__fmul_rn(seed[p], hab[p]), good[p]);
}

__global__ __launch_bounds__(256) void k_step(const float* __restrict__ xin,
                                              const float* __restrict__ good,
                                              float* __restrict__ xout,
                                              uint32_t a0, uint32_t a1,
                                              uint32_t b0, uint32_t b1) {
  __shared__ float xs[NSTG];                 // staged x (later overwritten w/ t)
  __shared__ unsigned char flg[TS * TS];     // per-output-pixel ub flag
  __shared__ unsigned short lst[NSTG];       // compacted cells needing jitter
  __shared__ int s_any, s_hasflag, s_cnt;
  const int tid = threadIdx.x;
  const int r0 = blockIdx.y * TS;
  const int c0 = blockIdx.x * TS;

  if (tid == 0) { s_any = 0; s_hasflag = 0; s_cnt = 0; }
  __syncthreads();

  // ---- phase 1: stage RAW x + halo (edge-clamp == -inf pad: values >= 0)
  int my_nz = 0;
  for (int s = tid; s < NSTG; s += 256) {
    int sr = s / PADW, sc = s - sr * PADW;
    int gr = r0 + sr - 1; gr = gr < 0 ? 0 : (gr > HH - 1 ? HH - 1 : gr);
    int gc = c0 + sc - 1; gc = gc < 0 ? 0 : (gc > WW - 1 ? WW - 1 : gc);
    float xv = xin[gr * WW + gc];
    if (xv != 0.0f) my_nz = 1;
    xs[s] = xv;
  }
  if (my_nz) s_any = 1;  // benign race
  __syncthreads();

  const int lc = tid & 63;   // local col 0..63
  const int lr0 = tid >> 6;  // local row base 0..3 (rows lr0+4j)

  if (!s_any) {  // whole staged region zero -> output tile is exactly 0
#pragma unroll
    for (int j = 0; j < 16; ++j)
      xout[(r0 + lr0 + 4 * j) * WW + (c0 + lc)] = 0.0f;
    return;
  }

  // ---- phase 2: upper-bound flags from RAW x
  float xv_sv[16];
  unsigned int fmask = 0;
  int my_flag = 0;
#pragma unroll
  for (int j = 0; j < 16; ++j) {
    int lr = lr0 + 4 * j;
    float xv = xs[(lr + 1) * PADW + (lc + 1)];
    const float* row = &xs[lr * PADW + lc];
    float M = fmaxf(fmaxf(row[0], row[1]), row[2]);
    row += PADW;
    M = fmaxf(M, fmaxf(fmaxf(row[0], row[1]), row[2]));
    row += PADW;
    M = fmaxf(M, fmaxf(fmaxf(row[0], row[1]), row[2]));
    int f = 0;
    if (__fsub_rn(M, xv) > 0.05f) {            // pre-test: good<1 => ub<=M
      float ub = __fmul_rn(M, good[(r0 + lr) * WW + (c0 + lc)]);
      if (__fsub_rn(ub, xv) > 0.05f) f = 1;    // ub test (v <= ub, monotone)
    }
    flg[lr * TS + lc] = (unsigned char)f;
    if (f) { my_flag = 1; fmask |= 1u << j; }
    xv_sv[j] = xv;
  }
  if (my_flag) s_hasflag = 1;  // benign race
  __syncthreads();

  if (!s_hasflag) {  // nothing can commit anywhere in tile -> out = x
#pragma unroll
    for (int j = 0; j < 16; ++j)
      xout[(r0 + lr0 + 4 * j) * WW + (c0 + lc)] = xv_sv[j];
    return;
  }

  // ---- phase 3: compact worklist of staged cells feeding a flagged pixel
  // output (or,oc) reads staged (or..or+2, oc..oc+2)  =>
  // staged (sr,sc) feeds outputs (sr-2..sr, sc-2..sc) clipped to [0,64)
  for (int s = tid; s < NSTG; s += 256) {
    if (xs[s] == 0.0f) continue;               // t = 0*s1 == +0, no draw
    int sr = s / PADW, sc = s - sr * PADW;
    int rlo = sr - 2 < 0 ? 0 : sr - 2, rhi = sr > TS - 1 ? TS - 1 : sr;
    int clo = sc - 2 < 0 ? 0 : sc - 2, chi = sc > TS - 1 ? TS - 1 : sc;
    int need = 0;
    for (int r = rlo; r <= rhi; ++r)
      for (int c = clo; c <= chi; ++c) need |= flg[r * TS + c];
    if (need) { int k = atomicAdd(&s_cnt, 1); lst[k] = (unsigned short)s; }
  }
  __syncthreads();

  // ---- phase 4: jitter only the needed cells (dense worklist, no div. waste)
  int cnt = s_cnt;
  for (int jj = tid; jj < cnt; jj += 256) {
    int s = lst[jj];
    int sr = s / PADW, sc = s - sr * PADW;
    int gr = r0 + sr - 1; gr = gr < 0 ? 0 : (gr > HH - 1 ? HH - 1 : gr);
    int gc = c0 + sc - 1; gc = gc < 0 ? 0 : (gc > WW - 1 ? WW - 1 : gc);
    float u = uniform01(a0, a1, (uint32_t)(gr * WW + gc));
    float s1 = __fadd_rn((float)(1.0 - 1e-4), __fmul_rn(1e-4f, u));
    xs[s] = __fmul_rn(xs[s], s1);
  }
  __syncthreads();

  // ---- phase 5: exact commit at flagged pixels only
#pragma unroll
  for (int j = 0; j < 16; ++j) {
    int lr = lr0 + 4 * j;
    int p = (r0 + lr) * WW + (c0 + lc);
    float xv = xv_sv[j];
    float out = xv;
    if ((fmask >> j) & 1u) {
      const float* row = &xs[lr * PADW + lc];
      float m = fmaxf(fmaxf(row[0], row[1]), row[2]);
      row += PADW;
      m = fmaxf(m, fmaxf(fmaxf(row[0], row[1]), row[2]));
      row += PADW;
      m = fmaxf(m, fmaxf(fmaxf(row[0], row[1]), row[2]));
      float v = __fmul_rn(m, good[p]);
      if (__fsub_rn(v, xv) > 0.05f) {          // exact test -> coin draw
        float u2 = uniform01(b0, b1, (uint32_t)p);
        if (u2 > 0.5f) out = v;
      }
    }
    xout[p] = out;
  }
}

extern "C" void kernel_launch(void* const* d_in, const int* in_sizes, int n_in,
                              void* d_out, int out_size, void* d_ws, size_t ws_size,
                              hipStream_t stream) {
  const float* seed = (const float*)d_in[0];
  const float* hab  = (const float*)d_in[1];
  const float* good = (const float*)d_in[2];
  float* bufA = (float*)d_out;  // x starts and ends here (100 = even steps)
  float* bufB = (float*)d_ws;

  k_init<<<dim3(NPIX / 256), dim3(256), 0, stream>>>(seed, hab, good, bufA);

  // sum(delta)==0.0 exactly (required for early exit) is unreachable once any
  // seed is nonzero (coin toss gives delta = -x < 0 somewhere) -> all 100 steps.
  dim3 grd(WW / TS, HH / TS), blk(256);
  for (int i = 0; i < 100; ++i) {
    uint32_t f0, f1, a0, a1, b0, b1;
    tf2x32(0u, 42u, 0u, (uint32_t)i, &f0, &f1);  // fold_in(key(42), i)
    tf2x32(f0, f1, 0u, 0u, &a0, &a1);            // split -> k1 (jitter)
    tf2x32(f0, f1, 0u, 1u, &b0, &b1);            // split -> k2 (coin)
    const float* xin = (i & 1) ? bufB : bufA;
    float* xout      = (i & 1) ? bufA : bufB;
    k_step<<<grd, blk, 0, stream>>>(xin, good, xout, a0, a1, b0, b1);
  }
}

// Round 5
// 2042.041 us; speedup vs baseline: 1.2749x; 1.2749x over previous
//
#include <hip/hip_runtime.h>
#include <stdint.h>

// RandomPropagate: 100 steps of jitter -> 3x3 maxpool -> coin mask -> goodness
// scale -> threshold commit, on a 2048x2048 f32 grid.
//
// Round 5: K-step fusion in LDS (K=8, 80x80 staged tile, halo 8) with
//  - per-tile convergence break: flag := fl(fl(M*good)-x) > 0.05 with
//    M = maxpool(RAW x). Since m = maxpool(t) <= M and fl is monotone,
//    v = fl(m*good) <= fl(M*good), so zero flags => no commit possible =>
//    x unchanged => zero flags forever (within launch) => fast-forward.
//  - vectorized strip maxpool: threads own 4x8 strips; rows read as
//    ds_read_b128 + 2 scalars, shared horizontal windows (~1 LDS instr/px).
//  - strip-granular RNG gating (R4 lesson: no per-cell scans/worklists):
//    jitter only where a neighboring strip flag is set (4 LDS byte reads),
//    t-maxpool + coin only inside flagged strips.
// Grid edges: staged with clamp; one dup ring layer (local row/col 7 and 72)
// refreshed from its source row/col after each commit pass (edge blocks only)
// -- clamp-duplication is max-idempotent == the reference's -inf pad.
// x ping-pongs d_ws <-> d_out across 13 launches (12x8 + 1x4 steps, odd
// count: init writes d_ws, final launch lands in d_out).
//
// PRNG: JAX threefry2x32, partitionable mode (bit-exact, absmax 0.0 R1-R4):
//   fold_in(key, i)       = tf2x32(key, (0, i))
//   split(F)[j]           = tf2x32(F,   (0, j))
//   random_bits32(key, p) = o0 ^ o1 of tf2x32(key, (0, p))
//   uniform01(bits)       = bitcast((bits>>9)|0x3f800000) - 1.0f
// All f32 math uses _rn intrinsics to forbid FMA contraction.

#define HH 2048
#define WW 2048
#define NPIX (HH * WW)
#define TS 64
#define HALO 8
#define SDIM 80            // 64 + 2*8, row stride (320 B, 16B-aligned)
#define K_MAX 8
#define SG_COLS 20         // 80/4 strip columns
#define SG_ROWS 10         // 80/8 strip rows
#define NSTRIP (SG_COLS * SG_ROWS)  // 200

// ---------- threefry2x32, exact JAX round structure ----------
__host__ __device__ __forceinline__ void tf2x32(uint32_t k0, uint32_t k1,
                                                uint32_t c0, uint32_t c1,
                                                uint32_t* o0, uint32_t* o1) {
  uint32_t ks2 = k0 ^ k1 ^ 0x1BD11BDAu;
  uint32_t x0 = c0 + k0, x1 = c1 + k1;
#define TFR(r) do { x0 += x1; x1 = (x1 << (r)) | (x1 >> (32 - (r))); x1 ^= x0; } while (0);
  TFR(13) TFR(15) TFR(26) TFR(6)
  x0 += k1; x1 += ks2 + 1u;
  TFR(17) TFR(29) TFR(16) TFR(24)
  x0 += ks2; x1 += k0 + 2u;
  TFR(13) TFR(15) TFR(26) TFR(6)
  x0 += k0; x1 += k1 + 3u;
  TFR(17) TFR(29) TFR(16) TFR(24)
  x0 += k1; x1 += ks2 + 4u;
  TFR(13) TFR(15) TFR(26) TFR(6)
  x0 += ks2; x1 += k0 + 5u;
#undef TFR
  *o0 = x0; *o1 = x1;
}

__device__ __forceinline__ float uniform01(uint32_t ka, uint32_t kb, uint32_t p) {
  uint32_t o0, o1;
  tf2x32(ka, kb, 0u, p, &o0, &o1);
  uint32_t bits = o0 ^ o1;  // partitionable 32-bit XOR fold
  return __uint_as_float((bits >> 9) | 0x3F800000u) - 1.0f;
}

struct Keys {
  uint32_t a0[K_MAX], a1[K_MAX], b0[K_MAX], b1[K_MAX];
  int K;
};

// x0 = seed * habitat * goodness  (seed is exactly 0/1, so rounding is exact)
__global__ void k_init(const float* __restrict__ seed,
                       const float* __restrict__ hab,
                       const float* __restrict__ good,
                       float* __restrict__ x) {
  int p = blockIdx.x * blockDim.x + threadIdx.x;
  if (p >= NPIX) return;
  x[p] = __fmul_rn(__fmul_rn(seed[p], hab[p]), good[p]);
}

// 3x3 max over an 80x80 LDS buffer for one 4-col x 8-row strip at (R, C),
// C % 4 == 0. Rows outside [0,80) contribute 0 (only feeds cells that are
// masked out by the valid rect). Optionally captures the strip's own cells.
template <bool GRAB_CENTER>
__device__ __forceinline__ void strip_max9(const float* buf, int R, int C,
                                           float M[8][4], float cx[8][4]) {
  float h[10][4];
#pragma unroll
  for (int ir = 0; ir < 10; ++ir) {
    int r = R - 1 + ir;
    float w0, w1, w2, w3, w4, w5;
    if (r < 0 || r >= SDIM) {
      w0 = w1 = w2 = w3 = w4 = w5 = 0.0f;
    } else {
      const float* rowp = buf + r * SDIM;
      float4 mid = *reinterpret_cast<const float4*>(rowp + C);  // ds_read_b128
      w1 = mid.x; w2 = mid.y; w3 = mid.z; w4 = mid.w;
      w0 = (C > 0) ? rowp[C - 1] : 0.0f;          // feeds only masked col
      w5 = (C + 4 < SDIM) ? rowp[C + 4] : 0.0f;   // feeds only masked col
    }
    if (GRAB_CENTER && ir >= 1 && ir <= 8) {
      cx[ir - 1][0] = w1; cx[ir - 1][1] = w2;
      cx[ir - 1][2] = w3; cx[ir - 1][3] = w4;
    }
    float p01 = fmaxf(w0, w1), p12 = fmaxf(w1, w2), p23 = fmaxf(w2, w3),
          p34 = fmaxf(w3, w4), p45 = fmaxf(w4, w5);
    h[ir][0] = fmaxf(p01, w2); h[ir][1] = fmaxf(p12, w3);
    h[ir][2] = fmaxf(p23, w4); h[ir][3] = fmaxf(p45, p34);  // max3(w3,w4,w5)
  }
#pragma unroll
  for (int j = 0; j < 8; ++j)
#pragma unroll
    for (int c = 0; c < 4; ++c)
      M[j][c] = fmaxf(fmaxf(h[j][c], h[j + 1][c]), h[j + 2][c]);
}

__global__ __launch_bounds__(256, 3) void k_fused(const float* __restrict__ xin,
                                                  const float* __restrict__ good,
                                                  float* __restrict__ xout,
                                                  Keys kk) {
  __shared__ __align__(16) float xs[SDIM * SDIM];  // current x
  __shared__ __align__(16) float ts[SDIM * SDIM];  // jittered field (sparse)
  __shared__ unsigned char sf[NSTRIP];             // per-strip ub flags
  __shared__ int s_any;

  const int tid = threadIdx.x;
  const int r0b = blockIdx.y * TS, c0b = blockIdx.x * TS;  // tile origin
  const int r0g = r0b - HALO, c0g = c0b - HALO;            // staged origin
  const bool top = (r0b == 0), bot = (r0b == HH - TS);
  const bool lef = (c0b == 0), rig = (c0b == WW - TS);
  const bool edge = top || bot || lef || rig;

  // strip ownership (threads 200..255 idle in strip passes)
  const int gx = tid % SG_COLS, gy = tid / SG_COLS;
  const int R = 8 * gy, C = 4 * gx;

  // ---- stage raw x (clamped: duplication is max-idempotent == -inf pad)
  for (int idx = tid; idx < SDIM * SDIM; idx += 256) {
    int sr = idx / SDIM, sc = idx - sr * SDIM;
    int gr = r0g + sr; gr = gr < 0 ? 0 : (gr > HH - 1 ? HH - 1 : gr);
    int gc = c0g + sc; gc = gc < 0 ? 0 : (gc > WW - 1 ? WW - 1 : gc);
    xs[idx] = xin[gr * WW + gc];
  }

  for (int s = 0; s < kk.K; ++s) {
    // valid (exactly updatable) rect this step, local coords
    const int rlo = top ? HALO : s + 1;
    const int rhi = bot ? HALO + TS - 1 : SDIM - 2 - s;
    const int clo = lef ? HALO : s + 1;
    const int chi = rig ? HALO + TS - 1 : SDIM - 2 - s;

    if (tid == 0) s_any = 0;
    __syncthreads();  // also covers staging / previous commit visibility

    // ---- pass A: ub flags from RAW x (jitter-independent upper bound)
    unsigned int cand = 0;
    float cx[8][4];
    const bool live = (tid < NSTRIP) &&
                      !(R > rhi || R + 7 < rlo || C > chi || C + 3 < clo);
    if (live) {
      float M[8][4];
      strip_max9<true>(xs, R, C, M, cx);
#pragma unroll
      for (int j = 0; j < 8; ++j) {
#pragma unroll
        for (int c = 0; c < 4; ++c) {
          int rr = R + j, cc = C + c;
          if (rr < rlo || rr > rhi || cc < clo || cc > chi) continue;
          float xv = cx[j][c];
          if (__fsub_rn(M[j][c], xv) > 0.05f) {   // pre-test: g<1 => ub <= M
            float g = good[(r0g + rr) * WW + (c0g + cc)];
            float ub = __fmul_rn(M[j][c], g);
            if (__fsub_rn(ub, xv) > 0.05f) cand |= 1u << (j * 4 + c);
          }
        }
      }
    }
    if (tid < NSTRIP) sf[tid] = (unsigned char)(cand != 0);
    if (cand) s_any = 1;  // benign race
    __syncthreads();

    if (!s_any) break;  // no commit possible now or at any later step

    // ---- jitter pass: only cells feeding a flagged strip (4 flag lookups)
    {
      const int jr_lo = rlo - 1, jr_hi = rhi + 1;
      const int jc_lo = clo - 1, jc_hi = chi + 1;
      const int nrows = jr_hi - jr_lo + 1;
      for (int idx = tid; idx < nrows * SDIM; idx += 256) {
        int er = idx / SDIM, sc = idx - er * SDIM;
        if (sc < jc_lo || sc > jc_hi) continue;
        int sr = jr_lo + er;
        int ra = sr - 1 < 0 ? 0 : sr - 1, rb = sr + 1 > SDIM - 1 ? SDIM - 1 : sr + 1;
        int ca = sc - 1 < 0 ? 0 : sc - 1, cb = sc + 1 > SDIM - 1 ? SDIM - 1 : sc + 1;
        int fr0 = ra >> 3, fr1 = rb >> 3, fc0 = ca >> 2, fc1 = cb >> 2;
        unsigned char f = sf[fr0 * SG_COLS + fc0] | sf[fr0 * SG_COLS + fc1] |
                          sf[fr1 * SG_COLS + fc0] | sf[fr1 * SG_COLS + fc1];
        if (!f) continue;  // never read by pass B
        float xv = xs[sr * SDIM + sc];
        float tv = 0.0f;
        if (xv != 0.0f) {  // t = 0 * s1 == +0 exactly, draw skippable
          int gr = r0g + sr; gr = gr < 0 ? 0 : (gr > HH - 1 ? HH - 1 : gr);
          int gc = c0g + sc; gc = gc < 0 ? 0 : (gc > WW - 1 ? WW - 1 : gc);
          float u = uniform01(kk.a0[s], kk.a1[s], (uint32_t)(gr * WW + gc));
          float s1 = __fadd_rn((float)(1.0 - 1e-4), __fmul_rn(1e-4f, u));
          tv = __fmul_rn(xv, s1);
        }
        ts[sr * SDIM + sc] = tv;
      }
    }
    __syncthreads();

    // ---- pass B: exact maxpool(t) + coin + commit, flagged strips only
    if (live && cand) {
      float Mt[8][4], dmy[8][4];
      strip_max9<false>(ts, R, C, Mt, dmy);
      unsigned int m = cand;
      while (m) {
        int b = __builtin_ctz(m); m &= m - 1;
        int j = b >> 2, c = b & 3;
        float xv = cx[j][c];
        int gp = (r0g + R + j) * WW + (c0g + C + c);  // in rect => in bounds
        float g = good[gp];
        float v = __fmul_rn(Mt[j][c], g);
        if (__fsub_rn(v, xv) > 0.05f) {       // exact test -> coin draw
          float u2 = uniform01(kk.b0[s], kk.b1[s], (uint32_t)gp);
          if (u2 > 0.5f) xs[(R + j) * SDIM + (C + c)] = v;  // max(v,x)=v
        }
      }
    }
    __syncthreads();

    // ---- refresh dup ring for grid-edge tiles (only layer 7/72 is ever read)
    if (edge) {
      if (top) for (int c = tid; c < SDIM; c += 256) xs[7 * SDIM + c] = xs[8 * SDIM + c];
      if (bot) for (int c = tid; c < SDIM; c += 256) xs[72 * SDIM + c] = xs[71 * SDIM + c];
      __syncthreads();
      if (lef) for (int r = tid; r < SDIM; r += 256) xs[r * SDIM + 7] = xs[r * SDIM + 8];
      if (rig) for (int r = tid; r < SDIM; r += 256) xs[r * SDIM + 72] = xs[r * SDIM + 71];
      __syncthreads();
    }
  }

  // ---- write back central 64x64
  __syncthreads();
  for (int idx = tid; idx < TS * TS; idx += 256) {
    int r = idx >> 6, c = idx & 63;
    xout[(r0b + r) * WW + (c0b + c)] = xs[(r + HALO) * SDIM + (c + HALO)];
  }
}

extern "C" void kernel_launch(void* const* d_in, const int* in_sizes, int n_in,
                              void* d_out, int out_size, void* d_ws, size_t ws_size,
                              hipStream_t stream) {
  const float* seed = (const float*)d_in[0];
  const float* hab  = (const float*)d_in[1];
  const float* good = (const float*)d_in[2];
  float* bufA = (float*)d_out;
  float* bufB = (float*)d_ws;

  // 13 launches (12x8 + 1x4): init -> bufB, odd launch count ends in bufA.
  k_init<<<dim3(NPIX / 256), dim3(256), 0, stream>>>(seed, hab, good, bufB);

  // sum(delta)==0.0 exactly (required for early exit) is unreachable once any
  // seed is nonzero (coin toss gives delta = -x < 0 somewhere) -> all 100 steps.
  float* cur = bufB;
  dim3 grd(WW / TS, HH / TS), blk(256);
  for (int base = 0; base < 100; base += K_MAX) {
    Keys kk;
    kk.K = (100 - base < K_MAX) ? (100 - base) : K_MAX;
    for (int s = 0; s < kk.K; ++s) {
      uint32_t f0, f1;
      tf2x32(0u, 42u, 0u, (uint32_t)(base + s), &f0, &f1);  // fold_in(key, i)
      tf2x32(f0, f1, 0u, 0u, &kk.a0[s], &kk.a1[s]);         // split -> jitter
      tf2x32(f0, f1, 0u, 1u, &kk.b0[s], &kk.b1[s]);         // split -> coin
    }
    float* nxt = (cur == bufB) ? bufA : bufB;
    k_fused<<<grd, blk, 0, stream>>>(cur, good, nxt, kk);
    cur = nxt;
  }
  // cur == bufA == d_out here (13 toggles from bufB)
}

// Round 6
// 1684.233 us; speedup vs baseline: 1.5457x; 1.2124x over previous
//
#include <hip/hip_runtime.h>
#include <stdint.h>

// RandomPropagate: 100 steps of jitter -> 3x3 maxpool -> coin mask -> goodness
// scale -> threshold commit, on a 2048x2048 f32 grid.
//
// Round 6: wave-native fused tiles. Staged tile 64x64 (= one wave per row),
// output 32x32, halo 16, K=16 steps/launch -> 7 launches.
//  - ub flag (proven monotone bound, R4/R5): flag := fl(fl(M*good)-x) > THR
//    with M = maxpool3(RAW x); m=maxpool3(t) <= M and good<1 => no flag =>
//    no commit possible now or later => per-tile break.
//  - incremental flags: flag(px) depends on x|3x3(px) only => changes only
//    within distance 1 of a commit => re-eval dilate1(cmask) after step 0.
//  - per-row uint64 masks via __ballot; maxpool = 3 LDS reads + 2 shuffles.
//  - jitter drawn only at cells within 1 of a live flag and x!=0; coin drawn
//    only at flagged px passing the exact test. All consumed RNG bits are
//    bit-identical to the reference stream (per-pixel counters).
// Grid edges: staged with clamp (max-idempotent == -inf pad); dup ring layer
// (local row/col 15 and 48) refreshed from its source after each commit pass.
// x ping-pongs d_ws <-> d_out across 7 launches (odd -> ends in d_out).
//
// PRNG: JAX threefry2x32, partitionable mode (bit-exact, absmax 0.0 R1-R5):
//   fold_in(key, i)       = tf2x32(key, (0, i))
//   split(F)[j]           = tf2x32(F,   (0, j))
//   random_bits32(key, p) = o0 ^ o1 of tf2x32(key, (0, p))
//   uniform01(bits)       = bitcast((bits>>9)|0x3f800000) - 1.0f
// All f32 math uses _rn intrinsics to forbid FMA contraction.

#define HH 2048
#define WW 2048
#define NPIX (HH * WW)
#define SD 64           // staged tile side (1 wave per row)
#define OT 32           // output tile side
#define HALO 16
#define K_MAX 16
#define NB (WW / OT)    // 64 tile-blocks per side

// ---------- threefry2x32, exact JAX round structure ----------
__host__ __device__ __forceinline__ void tf2x32(uint32_t k0, uint32_t k1,
                                                uint32_t c0, uint32_t c1,
                                                uint32_t* o0, uint32_t* o1) {
  uint32_t ks2 = k0 ^ k1 ^ 0x1BD11BDAu;
  uint32_t x0 = c0 + k0, x1 = c1 + k1;
#define TFR(r) do { x0 += x1; x1 = (x1 << (r)) | (x1 >> (32 - (r))); x1 ^= x0; } while (0);
  TFR(13) TFR(15) TFR(26) TFR(6)
  x0 += k1; x1 += ks2 + 1u;
  TFR(17) TFR(29) TFR(16) TFR(24)
  x0 += ks2; x1 += k0 + 2u;
  TFR(13) TFR(15) TFR(26) TFR(6)
  x0 += k0; x1 += k1 + 3u;
  TFR(17) TFR(29) TFR(16) TFR(24)
  x0 += k1; x1 += ks2 + 4u;
  TFR(13) TFR(15) TFR(26) TFR(6)
  x0 += ks2; x1 += k0 + 5u;
#undef TFR
  *o0 = x0; *o1 = x1;
}

__device__ __forceinline__ float uniform01(uint32_t ka, uint32_t kb, uint32_t p) {
  uint32_t o0, o1;
  tf2x32(ka, kb, 0u, p, &o0, &o1);
  uint32_t bits = o0 ^ o1;  // partitionable 32-bit XOR fold
  return __uint_as_float((bits >> 9) | 0x3F800000u) - 1.0f;
}

struct Keys {
  uint32_t a0[K_MAX], a1[K_MAX], b0[K_MAX], b1[K_MAX];
  int K;
};

// x0 = seed * habitat * goodness  (seed is exactly 0/1, so rounding is exact)
__global__ void k_init(const float* __restrict__ seed,
                       const float* __restrict__ hab,
                       const float* __restrict__ good,
                       float* __restrict__ x) {
  int p = blockIdx.x * blockDim.x + threadIdx.x;
  if (p >= NPIX) return;
  x[p] = __fmul_rn(__fmul_rn(seed[p], hab[p]), good[p]);
}

__global__ __launch_bounds__(256) void k_fused(const float* __restrict__ xin,
                                               const float* __restrict__ good,
                                               float* __restrict__ xout,
                                               Keys kk) {
  __shared__ float xs[SD * SD];                // current x
  __shared__ float ts[SD * SD];                // jittered field (frontier only)
  __shared__ unsigned long long fm[SD];        // per-row flag mask
  __shared__ unsigned long long cm[SD];        // per-row commit mask (this step)
  __shared__ int s_any;

  const int tid = threadIdx.x;
  const int wv = tid >> 6, ln = tid & 63;      // wave id (0..3), lane (=col)
  const int r0b = blockIdx.y * OT, c0b = blockIdx.x * OT;  // output origin
  const int r0g = r0b - HALO, c0g = c0b - HALO;            // staged origin
  const bool top = (blockIdx.y == 0), bot = (blockIdx.y == NB - 1);
  const bool lef = (blockIdx.x == 0), rig = (blockIdx.x == NB - 1);
  const bool edge = top || bot || lef || rig;

  // ---- stage raw x (clamped: duplication is max-idempotent == -inf pad)
  for (int idx = tid; idx < SD * SD; idx += 256) {
    int sr = idx >> 6, sc = idx & 63;
    int gr = r0g + sr; gr = gr < 0 ? 0 : (gr > HH - 1 ? HH - 1 : gr);
    int gc = c0g + sc; gc = gc < 0 ? 0 : (gc > WW - 1 ? WW - 1 : gc);
    xs[idx] = xin[gr * WW + gc];
  }
  if (tid < SD) { fm[tid] = 0ULL; cm[tid] = 0ULL; }
  if (tid == 0) s_any = 0;
  __syncthreads();

  for (int s = 0; s < kk.K; ++s) {
    // exactly-updatable rect this step (local coords)
    const int rlo = top ? HALO : s + 1;
    const int rhi = bot ? HALO + OT - 1 : SD - 2 - s;
    const int clo = lef ? HALO : s + 1;
    const int chi = rig ? HALO + OT - 1 : SD - 2 - s;
    const unsigned long long colw =
        (~0ULL >> (63 - (chi - clo))) << clo;  // bits clo..chi

    // ---- pass A: flag eval (full at s=0; dilate1(cm) re-eval after)
    for (int r = rlo + wv; r <= rhi; r += 4) {
      unsigned long long f = fm[r];
      bool evaluate = false;
      unsigned long long d = colw;             // lanes to (re)evaluate
      if (s == 0) {
        evaluate = true;
      } else {
        unsigned long long cn = cm[r - 1] | cm[r] | cm[r + 1];
        if (cn) {
          d = (cn | (cn << 1) | (cn >> 1)) & colw;
          evaluate = (d != 0ULL);
        }
      }
      if (evaluate) {
        float a = xs[((r - 1) << 6) + ln];
        float b = xs[(r << 6) + ln];
        float c = xs[((r + 1) << 6) + ln];
        float vv = fmaxf(fmaxf(a, b), c);      // vertical max, own col
        float hl = __shfl(vv, ln - 1);         // junk at lane 0 (never valid)
        float hr = __shfl(vv, ln + 1);         // junk at lane 63 (never valid)
        float M = fmaxf(fmaxf(hl, vv), hr);
        bool flag = false;
        if ((d >> ln) & 1ULL) {
          float xv = b;
          if (__fsub_rn(M, xv) > 0.05f) {      // pre-test: good<1 => ub <= M
            float g = good[(r0g + r) * WW + (c0g + ln)];
            if (__fsub_rn(__fmul_rn(M, g), xv) > 0.05f) flag = true;
          }
        }
        f = (f & ~d) | (__ballot(flag) & d);
        if (ln == 0) fm[r] = f;
      }
      if ((f & colw) && ln == 0) s_any = 1;    // benign race
    }
    __syncthreads();
    int go = s_any;
    __syncthreads();
    if (tid == 0) s_any = 0;
    if (!go) break;  // no commit possible now => x frozen => never again

    // ---- clear cm + jitter frontier cells (rows/cols within 1 of a flag)
    if (tid < SD) cm[tid] = 0ULL;
    for (int r = rlo - 1 + wv; r <= rhi + 1; r += 4) {
      unsigned long long f = 0ULL;
      if (r - 1 >= rlo && r - 1 <= rhi) f |= fm[r - 1];
      if (r     >= rlo && r     <= rhi) f |= fm[r];
      if (r + 1 >= rlo && r + 1 <= rhi) f |= fm[r + 1];
      f &= colw;
      if (!f) continue;                        // wave skips whole row
      unsigned long long need = f | (f << 1) | (f >> 1);
      if ((need >> ln) & 1ULL) {
        float xv = xs[(r << 6) + ln];
        float tv = 0.0f;
        if (xv != 0.0f) {                      // t = 0*s1 == +0 exactly
          int gr = r0g + r;  gr = gr < 0 ? 0 : (gr > HH - 1 ? HH - 1 : gr);
          int gc = c0g + ln; gc = gc < 0 ? 0 : (gc > WW - 1 ? WW - 1 : gc);
          float u = uniform01(kk.a0[s], kk.a1[s], (uint32_t)(gr * WW + gc));
          float s1 = __fadd_rn((float)(1.0 - 1e-4), __fmul_rn(1e-4f, u));
          tv = __fmul_rn(xv, s1);
        }
        ts[(r << 6) + ln] = tv;
      }
    }
    __syncthreads();

    // ---- pass B: exact maxpool(t) + coin + commit at flagged px
    for (int r = rlo + wv; r <= rhi; r += 4) {
      unsigned long long wf = fm[r] & colw;
      if (!wf) continue;                       // wave skips whole row
      // unwritten ts garbage is only produced at lanes >1 away from any flag
      // and is never consumed (each lane's max uses lanes ln-1..ln+1 only)
      float t0 = ts[((r - 1) << 6) + ln];
      float t1 = ts[(r << 6) + ln];
      float t2 = ts[((r + 1) << 6) + ln];
      float vt = fmaxf(fmaxf(t0, t1), t2);
      float hl = __shfl(vt, ln - 1);
      float hr = __shfl(vt, ln + 1);
      float m = fmaxf(fmaxf(hl, vt), hr);
      bool ok = false;
      float v = 0.0f;
      if ((wf >> ln) & 1ULL) {
        int gp = (r0g + r) * WW + (c0g + ln);  // in rect => in bounds
        float xv = xs[(r << 6) + ln];
        v = __fmul_rn(m, good[gp]);
        if (__fsub_rn(v, xv) > 0.05f) {        // exact test -> coin draw
          float u2 = uniform01(kk.b0[s], kk.b1[s], (uint32_t)gp);
          ok = (u2 > 0.5f);
        }
      }
      unsigned long long bal = __ballot(ok);
      if (ok) xs[(r << 6) + ln] = v;           // max(v,x)=v since v-x>THR>0
      if (bal && ln == 0) cm[r] = bal;
    }
    __syncthreads();

    // ---- refresh dup ring for grid-edge tiles (only layer 15/48 is read)
    if (edge) {
      if (top && tid < SD) xs[(15 << 6) + tid] = xs[(16 << 6) + tid];
      if (bot && tid < SD) xs[(48 << 6) + tid] = xs[(47 << 6) + tid];
      __syncthreads();
      if (lef && tid < SD) xs[(tid << 6) + 15] = xs[(tid << 6) + 16];
      if (rig && tid < SD) xs[(tid << 6) + 48] = xs[(tid << 6) + 47];
      __syncthreads();
    }
  }

  // ---- write back central 32x32 (exit paths all end on a barrier)
  for (int idx = tid; idx < OT * OT; idx += 256) {
    int r = idx >> 5, c = idx & 31;
    xout[(r0b + r) * WW + (c0b + c)] = xs[((r + HALO) << 6) + (c + HALO)];
  }
}

extern "C" void kernel_launch(void* const* d_in, const int* in_sizes, int n_in,
                              void* d_out, int out_size, void* d_ws, size_t ws_size,
                              hipStream_t stream) {
  const float* seed = (const float*)d_in[0];
  const float* hab  = (const float*)d_in[1];
  const float* good = (const float*)d_in[2];
  float* bufA = (float*)d_out;
  float* bufB = (float*)d_ws;

  // 7 fused launches (6x16 + 1x4): init -> bufB, odd count ends in bufA=d_out.
  k_init<<<dim3(NPIX / 256), dim3(256), 0, stream>>>(seed, hab, good, bufB);

  // sum(delta)==0.0 exactly (required for early exit) is unreachable once any
  // seed is nonzero (coin toss gives delta = -x < 0 somewhere) -> all 100 steps.
  float* cur = bufB;
  dim3 grd(NB, NB), blk(256);
  for (int base = 0; base < 100; base += K_MAX) {
    Keys kk;
    kk.K = (100 - base < K_MAX) ? (100 - base) : K_MAX;
    for (int s = 0; s < kk.K; ++s) {
      uint32_t f0, f1;
      tf2x32(0u, 42u, 0u, (uint32_t)(base + s), &f0, &f1);  // fold_in(key, i)
      tf2x32(f0, f1, 0u, 0u, &kk.a0[s], &kk.a1[s]);         // split -> jitter
      tf2x32(f0, f1, 0u, 1u, &kk.b0[s], &kk.b1[s]);         // split -> coin
    }
    float* nxt = (cur == bufB) ? bufA : bufB;
    k_fused<<<grd, blk, 0, stream>>>(cur, good, nxt, kk);
    cur = nxt;
  }
  // cur == bufA == d_out (7 toggles from bufB)
}

// Round 7
// 1636.165 us; speedup vs baseline: 1.5912x; 1.0294x over previous
//
#include <hip/hip_runtime.h>
#include <stdint.h>

// RandomPropagate: 100 steps of jitter -> 3x3 maxpool -> coin mask -> goodness
// scale -> threshold commit, on a 2048x2048 f32 grid.
//
// Round 7 = Round 6 (wave-native fused tiles, verified absmax 0.0) +
// cross-launch convergence skipping:
//  - status byte per tile, ping-ponged with x: 0 iff tile broke early (zero
//    ub-flags over a rect covering its central 32x32, state frozen after).
//  - skip rule: commits propagate <=1 px/step (Chebyshev); a central change
//    within a 16-step launch needs a step-0 flag inside the staged 64x64,
//    which is covered by the 3x3 neighborhood's central regions. So if own +
//    8 neighbor statuses are all 0 -> output == input bit-exactly -> float4
//    copy of central 32x32, write status 0, return (no staging/flags/RNG).
//  - interior blocks stage/write back via float4 (no clamp arithmetic).
// Core per-launch machinery unchanged from R6:
//  - ub flag (monotone bound): flag := fl(fl(M*good)-x) > THR, M=maxpool3(x);
//    m=maxpool3(t)<=M, good<1 => no flags => frozen => per-tile break.
//  - incremental flags: re-eval only dilate1(commit mask) after step 0.
//  - per-row uint64 masks via __ballot; maxpool = 3 LDS reads + 2 shuffles.
//  - jitter only within 1 of a live flag and x!=0; coin only at flagged px
//    passing the exact test. Consumed RNG bits identical to the reference.
//
// PRNG: JAX threefry2x32, partitionable mode (bit-exact, absmax 0.0 R1-R6):
//   fold_in(key, i)       = tf2x32(key, (0, i))
//   split(F)[j]           = tf2x32(F,   (0, j))
//   random_bits32(key, p) = o0 ^ o1 of tf2x32(key, (0, p))
//   uniform01(bits)       = bitcast((bits>>9)|0x3f800000) - 1.0f
// All f32 math uses _rn intrinsics to forbid FMA contraction.

#define HH 2048
#define WW 2048
#define NPIX (HH * WW)
#define SD 64           // staged tile side (1 wave per row)
#define OT 32           // output tile side
#define HALO 16
#define K_MAX 16
#define NB (WW / OT)    // 64 tile-blocks per side
#define NTILE (NB * NB)

// ---------- threefry2x32, exact JAX round structure ----------
__host__ __device__ __forceinline__ void tf2x32(uint32_t k0, uint32_t k1,
                                                uint32_t c0, uint32_t c1,
                                                uint32_t* o0, uint32_t* o1) {
  uint32_t ks2 = k0 ^ k1 ^ 0x1BD11BDAu;
  uint32_t x0 = c0 + k0, x1 = c1 + k1;
#define TFR(r) do { x0 += x1; x1 = (x1 << (r)) | (x1 >> (32 - (r))); x1 ^= x0; } while (0);
  TFR(13) TFR(15) TFR(26) TFR(6)
  x0 += k1; x1 += ks2 + 1u;
  TFR(17) TFR(29) TFR(16) TFR(24)
  x0 += ks2; x1 += k0 + 2u;
  TFR(13) TFR(15) TFR(26) TFR(6)
  x0 += k0; x1 += k1 + 3u;
  TFR(17) TFR(29) TFR(16) TFR(24)
  x0 += k1; x1 += ks2 + 4u;
  TFR(13) TFR(15) TFR(26) TFR(6)
  x0 += ks2; x1 += k0 + 5u;
#undef TFR
  *o0 = x0; *o1 = x1;
}

__device__ __forceinline__ float uniform01(uint32_t ka, uint32_t kb, uint32_t p) {
  uint32_t o0, o1;
  tf2x32(ka, kb, 0u, p, &o0, &o1);
  uint32_t bits = o0 ^ o1;  // partitionable 32-bit XOR fold
  return __uint_as_float((bits >> 9) | 0x3F800000u) - 1.0f;
}

struct Keys {
  uint32_t a0[K_MAX], a1[K_MAX], b0[K_MAX], b1[K_MAX];
  int K;
};

// x0 = seed*habitat*goodness (seed exactly 0/1 => rounding exact); also arm
// the launch-0 status array (all tiles active).
__global__ void k_init(const float* __restrict__ seed,
                       const float* __restrict__ hab,
                       const float* __restrict__ good,
                       float* __restrict__ x,
                       unsigned char* __restrict__ st) {
  int p = blockIdx.x * blockDim.x + threadIdx.x;
  if (p >= NPIX) return;
  x[p] = __fmul_rn(__fmul_rn(seed[p], hab[p]), good[p]);
  if (p < NTILE) st[p] = 1;
}

__global__ __launch_bounds__(256) void k_fused(const float* __restrict__ xin,
                                               const float* __restrict__ good,
                                               float* __restrict__ xout,
                                               const unsigned char* __restrict__ st_in,
                                               unsigned char* __restrict__ st_out,
                                               Keys kk) {
  __shared__ float xs[SD * SD];                // current x
  __shared__ float ts[SD * SD];                // jittered field (frontier only)
  __shared__ unsigned long long fm[SD];        // per-row flag mask
  __shared__ unsigned long long cm[SD];        // per-row commit mask (this step)
  __shared__ int s_any, s_skip;

  const int tid = threadIdx.x;
  const int wv = tid >> 6, ln = tid & 63;      // wave id (0..3), lane (=col)
  const int bx = blockIdx.x, by = blockIdx.y;
  const int tix = by * NB + bx;
  const int r0b = by * OT, c0b = bx * OT;      // output origin
  const int r0g = r0b - HALO, c0g = c0b - HALO;  // staged origin
  const bool top = (by == 0), bot = (by == NB - 1);
  const bool lef = (bx == 0), rig = (bx == NB - 1);
  const bool edge = top || bot || lef || rig;

  // ---- cross-launch skip check: own + 8 neighbors all quiet?
  {
    bool act = false;
    if (tid < 9) {
      int dy = tid / 3 - 1, dx = tid % 3 - 1;
      int ny = by + dy, nx = bx + dx;
      if (ny >= 0 && ny < NB && nx >= 0 && nx < NB)
        act = st_in[ny * NB + nx] != 0;
    }
    unsigned long long b = __ballot(act);      // meaningful in wave 0
    if (tid == 0) s_skip = (b == 0ULL);
    __syncthreads();
  }
  if (s_skip) {  // frozen for this whole launch: output == input bit-exactly
    int r = tid >> 3, c4 = tid & 7;            // 32 rows x 8 float4
    int off = (r0b + r) * WW + c0b + 4 * c4;
    *(float4*)(xout + off) = *(const float4*)(xin + off);
    if (tid == 0) st_out[tix] = 0;
    return;
  }

  // ---- stage raw x (clamped: duplication is max-idempotent == -inf pad)
  if (!edge) {
#pragma unroll
    for (int k = 0; k < 4; ++k) {
      int q = tid + 256 * k;                   // 1024 float4s
      int sr = q >> 4, c4 = q & 15;
      ((float4*)xs)[q] =
          *(const float4*)(xin + (r0g + sr) * WW + c0g + 4 * c4);
    }
  } else {
    for (int idx = tid; idx < SD * SD; idx += 256) {
      int sr = idx >> 6, sc = idx & 63;
      int gr = r0g + sr; gr = gr < 0 ? 0 : (gr > HH - 1 ? HH - 1 : gr);
      int gc = c0g + sc; gc = gc < 0 ? 0 : (gc > WW - 1 ? WW - 1 : gc);
      xs[idx] = xin[gr * WW + gc];
    }
  }
  if (tid < SD) { fm[tid] = 0ULL; cm[tid] = 0ULL; }
  if (tid == 0) s_any = 0;
  __syncthreads();

  int broke = 0;
  for (int s = 0; s < kk.K; ++s) {
    // exactly-updatable rect this step (local coords)
    const int rlo = top ? HALO : s + 1;
    const int rhi = bot ? HALO + OT - 1 : SD - 2 - s;
    const int clo = lef ? HALO : s + 1;
    const int chi = rig ? HALO + OT - 1 : SD - 2 - s;
    const unsigned long long colw =
        (~0ULL >> (63 - (chi - clo))) << clo;  // bits clo..chi

    // ---- pass A: flag eval (full at s=0; dilate1(cm) re-eval after)
    for (int r = rlo + wv; r <= rhi; r += 4) {
      unsigned long long f = fm[r];
      bool evaluate = false;
      unsigned long long d = colw;             // lanes to (re)evaluate
      if (s == 0) {
        evaluate = true;
      } else {
        unsigned long long cn = cm[r - 1] | cm[r] | cm[r + 1];
        if (cn) {
          d = (cn | (cn << 1) | (cn >> 1)) & colw;
          evaluate = (d != 0ULL);
        }
      }
      if (evaluate) {
        float a = xs[((r - 1) << 6) + ln];
        float b = xs[(r << 6) + ln];
        float c = xs[((r + 1) << 6) + ln];
        float vv = fmaxf(fmaxf(a, b), c);      // vertical max, own col
        float hl = __shfl(vv, ln - 1);         // junk at lane 0 (never valid)
        float hr = __shfl(vv, ln + 1);         // junk at lane 63 (never valid)
        float M = fmaxf(fmaxf(hl, vv), hr);
        bool flag = false;
        if ((d >> ln) & 1ULL) {
          float xv = b;
          if (__fsub_rn(M, xv) > 0.05f) {      // pre-test: good<1 => ub <= M
            float g = good[(r0g + r) * WW + (c0g + ln)];
            if (__fsub_rn(__fmul_rn(M, g), xv) > 0.05f) flag = true;
          }
        }
        f = (f & ~d) | (__ballot(flag) & d);
        if (ln == 0) fm[r] = f;
      }
      if ((f & colw) && ln == 0) s_any = 1;    // benign race
    }
    __syncthreads();
    int go = s_any;
    __syncthreads();
    if (tid == 0) s_any = 0;
    if (!go) { broke = 1; break; }  // zero flags over rect >= central, frozen

    // ---- clear cm + jitter frontier cells (rows/cols within 1 of a flag)
    if (tid < SD) cm[tid] = 0ULL;
    for (int r = rlo - 1 + wv; r <= rhi + 1; r += 4) {
      unsigned long long f = 0ULL;
      if (r - 1 >= rlo && r - 1 <= rhi) f |= fm[r - 1];
      if (r     >= rlo && r     <= rhi) f |= fm[r];
      if (r + 1 >= rlo && r + 1 <= rhi) f |= fm[r + 1];
      f &= colw;
      if (!f) continue;                        // wave skips whole row
      unsigned long long need = f | (f << 1) | (f >> 1);
      if ((need >> ln) & 1ULL) {
        float xv = xs[(r << 6) + ln];
        float tv = 0.0f;
        if (xv != 0.0f) {                      // t = 0*s1 == +0 exactly
          int gr = r0g + r;  gr = gr < 0 ? 0 : (gr > HH - 1 ? HH - 1 : gr);
          int gc = c0g + ln; gc = gc < 0 ? 0 : (gc > WW - 1 ? WW - 1 : gc);
          float u = uniform01(kk.a0[s], kk.a1[s], (uint32_t)(gr * WW + gc));
          float s1 = __fadd_rn((float)(1.0 - 1e-4), __fmul_rn(1e-4f, u));
          tv = __fmul_rn(xv, s1);
        }
        ts[(r << 6) + ln] = tv;
      }
    }
    __syncthreads();

    // ---- pass B: exact maxpool(t) + coin + commit at flagged px
    for (int r = rlo + wv; r <= rhi; r += 4) {
      unsigned long long wf = fm[r] & colw;
      if (!wf) continue;                       // wave skips whole row
      // unwritten ts garbage only exists >1 lane away from any flag and is
      // never consumed (each lane's max uses lanes ln-1..ln+1 only)
      float t0 = ts[((r - 1) << 6) + ln];
      float t1 = ts[(r << 6) + ln];
      float t2 = ts[((r + 1) << 6) + ln];
      float vt = fmaxf(fmaxf(t0, t1), t2);
      float hl = __shfl(vt, ln - 1);
      float hr = __shfl(vt, ln + 1);
      float m = fmaxf(fmaxf(hl, vt), hr);
      bool ok = false;
      float v = 0.0f;
      if ((wf >> ln) & 1ULL) {
        int gp = (r0g + r) * WW + (c0g + ln);  // in rect => in bounds
        float xv = xs[(r << 6) + ln];
        v = __fmul_rn(m, good[gp]);
        if (__fsub_rn(v, xv) > 0.05f) {        // exact test -> coin draw
          float u2 = uniform01(kk.b0[s], kk.b1[s], (uint32_t)gp);
          ok = (u2 > 0.5f);
        }
      }
      unsigned long long bal = __ballot(ok);
      if (ok) xs[(r << 6) + ln] = v;           // max(v,x)=v since v-x>THR>0
      if (bal && ln == 0) cm[r] = bal;
    }
    __syncthreads();

    // ---- refresh dup ring for grid-edge tiles (only layer 15/48 is read)
    if (edge) {
      if (top && tid < SD) xs[(15 << 6) + tid] = xs[(16 << 6) + tid];
      if (bot && tid < SD) xs[(48 << 6) + tid] = xs[(47 << 6) + tid];
      __syncthreads();
      if (lef && tid < SD) xs[(tid << 6) + 15] = xs[(tid << 6) + 16];
      if (rig && tid < SD) xs[(tid << 6) + 48] = xs[(tid << 6) + 47];
      __syncthreads();
    }
  }

  if (tid == 0) st_out[tix] = broke ? 0 : 1;

  // ---- write back central 32x32 (float4; exit paths all end on a barrier)
  {
    int r = tid >> 3, c4 = tid & 7;            // 32 rows x 8 float4
    *(float4*)(xout + (r0b + r) * WW + c0b + 4 * c4) =
        *(const float4*)(xs + ((r + HALO) << 6) + HALO + 4 * c4);
  }
}

extern "C" void kernel_launch(void* const* d_in, const int* in_sizes, int n_in,
                              void* d_out, int out_size, void* d_ws, size_t ws_size,
                              hipStream_t stream) {
  const float* seed = (const float*)d_in[0];
  const float* hab  = (const float*)d_in[1];
  const float* good = (const float*)d_in[2];
  float* bufA = (float*)d_out;
  float* bufB = (float*)d_ws;
  unsigned char* stA = (unsigned char*)d_ws + (16u << 20);  // after bufB
  unsigned char* stB = stA + NTILE;

  // 7 fused launches (6x16 + 1x4): init -> bufB, odd count ends in bufA=d_out.
  k_init<<<dim3(NPIX / 256), dim3(256), 0, stream>>>(seed, hab, good, bufB, stA);

  // sum(delta)==0.0 exactly (required for early exit) is unreachable once any
  // seed is nonzero (coin toss gives delta = -x < 0 somewhere) -> all 100 steps.
  float* cur = bufB;
  unsigned char* stIn = stA; unsigned char* stOut = stB;
  dim3 grd(NB, NB), blk(256);
  for (int base = 0; base < 100; base += K_MAX) {
    Keys kk;
    kk.K = (100 - base < K_MAX) ? (100 - base) : K_MAX;
    for (int s = 0; s < kk.K; ++s) {
      uint32_t f0, f1;
      tf2x32(0u, 42u, 0u, (uint32_t)(base + s), &f0, &f1);  // fold_in(key, i)
      tf2x32(f0, f1, 0u, 0u, &kk.a0[s], &kk.a1[s]);         // split -> jitter
      tf2x32(f0, f1, 0u, 1u, &kk.b0[s], &kk.b1[s]);         // split -> coin
    }
    float* nxt = (cur == bufB) ? bufA : bufB;
    k_fused<<<grd, blk, 0, stream>>>(cur, good, nxt, stIn, stOut, kk);
    cur = nxt;
    unsigned char* t = stIn; stIn = stOut; stOut = t;
  }
  // cur == bufA == d_out (7 toggles from bufB)
}

// Round 8
// 1277.867 us; speedup vs baseline: 2.0373x; 1.2804x over previous
//
#include <hip/hip_runtime.h>
#include <stdint.h>

// RandomPropagate: 100 steps of jitter -> 3x3 maxpool -> coin mask -> goodness
// scale -> threshold commit, on a 2048x2048 f32 grid.
//
// Round 8 = Round 7 (wave-native fused tiles + cross-launch skip, verified
// absmax 0.0) + row-bitmask-driven passes: the R6/R7 step loop scanned all
// ~54 rows in all 3 passes every step (~350 ops/thread/step of scan overhead
// -> the profiled 55% VALUBusy). Now:
//  - flagrows (bit r = fm[r]!=0) and commitrows (bit r = commits in row r)
//    kept as 2x u32 LDS words, updated with 32-bit atomics by the same ln==0
//    lanes that write fm/cm.
//  - pass A re-evals rows in dilate1(commitrows) ∩ rect via ctz loop;
//    jitter covers dilate1(flagrows) ∩ range; pass B covers flagrows ∩ rect.
//    Rows round-robin over the 4 waves by set-bit ordinal (uniform loop).
//  - break test = (flagrows ∩ rect)==0, one uniform LDS read; s_any and one
//    barrier per step removed. cm guarded by commitrows (no clearing pass).
//  - edge dup-ring refresh gated on commitrows!=0.
// Values, flag algebra, and every consumed RNG bit identical to R6/R7.
//
// PRNG: JAX threefry2x32, partitionable mode (bit-exact, absmax 0.0 R1-R7):
//   fold_in(key, i)       = tf2x32(key, (0, i))
//   split(F)[j]           = tf2x32(F,   (0, j))
//   random_bits32(key, p) = o0 ^ o1 of tf2x32(key, (0, p))
//   uniform01(bits)       = bitcast((bits>>9)|0x3f800000) - 1.0f
// All f32 math uses _rn intrinsics to forbid FMA contraction.

#define HH 2048
#define WW 2048
#define NPIX (HH * WW)
#define SD 64           // staged tile side (1 wave per row)
#define OT 32           // output tile side
#define HALO 16
#define K_MAX 16
#define NB (WW / OT)    // 64 tile-blocks per side
#define NTILE (NB * NB)

// ---------- threefry2x32, exact JAX round structure ----------
__host__ __device__ __forceinline__ void tf2x32(uint32_t k0, uint32_t k1,
                                                uint32_t c0, uint32_t c1,
                                                uint32_t* o0, uint32_t* o1) {
  uint32_t ks2 = k0 ^ k1 ^ 0x1BD11BDAu;
  uint32_t x0 = c0 + k0, x1 = c1 + k1;
#define TFR(r) do { x0 += x1; x1 = (x1 << (r)) | (x1 >> (32 - (r))); x1 ^= x0; } while (0);
  TFR(13) TFR(15) TFR(26) TFR(6)
  x0 += k1; x1 += ks2 + 1u;
  TFR(17) TFR(29) TFR(16) TFR(24)
  x0 += ks2; x1 += k0 + 2u;
  TFR(13) TFR(15) TFR(26) TFR(6)
  x0 += k0; x1 += k1 + 3u;
  TFR(17) TFR(29) TFR(16) TFR(24)
  x0 += k1; x1 += ks2 + 4u;
  TFR(13) TFR(15) TFR(26) TFR(6)
  x0 += ks2; x1 += k0 + 5u;
#undef TFR
  *o0 = x0; *o1 = x1;
}

__device__ __forceinline__ float uniform01(uint32_t ka, uint32_t kb, uint32_t p) {
  uint32_t o0, o1;
  tf2x32(ka, kb, 0u, p, &o0, &o1);
  uint32_t bits = o0 ^ o1;  // partitionable 32-bit XOR fold
  return __uint_as_float((bits >> 9) | 0x3F800000u) - 1.0f;
}

__device__ __forceinline__ unsigned long long dil1(unsigned long long m) {
  return m | (m << 1) | (m >> 1);
}
__device__ __forceinline__ unsigned long long rmask(int lo, int hi) {
  return (~0ULL >> (63 - (hi - lo))) << lo;  // bits lo..hi
}

struct Keys {
  uint32_t a0[K_MAX], a1[K_MAX], b0[K_MAX], b1[K_MAX];
  int K;
};

// x0 = seed*habitat*goodness (seed exactly 0/1 => rounding exact); also arm
// the launch-0 status array (all tiles active).
__global__ void k_init(const float* __restrict__ seed,
                       const float* __restrict__ hab,
                       const float* __restrict__ good,
                       float* __restrict__ x,
                       unsigned char* __restrict__ st) {
  int p = blockIdx.x * blockDim.x + threadIdx.x;
  if (p >= NPIX) return;
  x[p] = __fmul_rn(__fmul_rn(seed[p], hab[p]), good[p]);
  if (p < NTILE) st[p] = 1;
}

__global__ __launch_bounds__(256) void k_fused(const float* __restrict__ xin,
                                               const float* __restrict__ good,
                                               float* __restrict__ xout,
                                               const unsigned char* __restrict__ st_in,
                                               unsigned char* __restrict__ st_out,
                                               Keys kk) {
  __shared__ float xs[SD * SD];                // current x
  __shared__ float ts[SD * SD];                // jittered field (frontier only)
  __shared__ unsigned long long fm[SD];        // per-row flag mask
  __shared__ unsigned long long cm[SD];        // commit masks (crw-guarded)
  __shared__ unsigned int s_flr[2];            // flagrows bitmask (lo/hi)
  __shared__ unsigned int s_crw[2];            // commitrows bitmask (lo/hi)
  __shared__ int s_skip;

  const int tid = threadIdx.x;
  const int wv = tid >> 6, ln = tid & 63;      // wave id (0..3), lane (=col)
  const int bx = blockIdx.x, by = blockIdx.y;
  const int tix = by * NB + bx;
  const int r0b = by * OT, c0b = bx * OT;      // output origin
  const int r0g = r0b - HALO, c0g = c0b - HALO;  // staged origin
  const bool top = (by == 0), bot = (by == NB - 1);
  const bool lef = (bx == 0), rig = (bx == NB - 1);
  const bool edge = top || bot || lef || rig;

  // ---- cross-launch skip check: own + 8 neighbors all quiet?
  {
    bool act = false;
    if (tid < 9) {
      int dy = tid / 3 - 1, dx = tid % 3 - 1;
      int ny = by + dy, nx = bx + dx;
      if (ny >= 0 && ny < NB && nx >= 0 && nx < NB)
        act = st_in[ny * NB + nx] != 0;
    }
    unsigned long long b = __ballot(act);      // meaningful in wave 0
    if (tid == 0) s_skip = (b == 0ULL);
    __syncthreads();
  }
  if (s_skip) {  // frozen for this whole launch: output == input bit-exactly
    int r = tid >> 3, c4 = tid & 7;            // 32 rows x 8 float4
    int off = (r0b + r) * WW + c0b + 4 * c4;
    *(float4*)(xout + off) = *(const float4*)(xin + off);
    if (tid == 0) st_out[tix] = 0;
    return;
  }

  // ---- stage raw x (clamped: duplication is max-idempotent == -inf pad)
  if (!edge) {
#pragma unroll
    for (int k = 0; k < 4; ++k) {
      int q = tid + 256 * k;                   // 1024 float4s
      int sr = q >> 4, c4 = q & 15;
      ((float4*)xs)[q] =
          *(const float4*)(xin + (r0g + sr) * WW + c0g + 4 * c4);
    }
  } else {
    for (int idx = tid; idx < SD * SD; idx += 256) {
      int sr = idx >> 6, sc = idx & 63;
      int gr = r0g + sr; gr = gr < 0 ? 0 : (gr > HH - 1 ? HH - 1 : gr);
      int gc = c0g + sc; gc = gc < 0 ? 0 : (gc > WW - 1 ? WW - 1 : gc);
      xs[idx] = xin[gr * WW + gc];
    }
  }
  if (tid < SD) fm[tid] = 0ULL;
  if (tid < 2) { s_flr[tid] = 0u; s_crw[tid] = 0u; }
  __syncthreads();

  int broke = 0;
  for (int s = 0; s < kk.K; ++s) {
    // exactly-updatable rect this step (local coords)
    const int rlo = top ? HALO : s + 1;
    const int rhi = bot ? HALO + OT - 1 : SD - 2 - s;
    const int clo = lef ? HALO : s + 1;
    const int chi = rig ? HALO + OT - 1 : SD - 2 - s;
    const unsigned long long colw = rmask(clo, chi);
    const unsigned long long rowsrect = rmask(rlo, rhi);
    const unsigned long long crw_prev =
        s_crw[0] | ((unsigned long long)s_crw[1] << 32);

    // ---- pass A: flag eval (full at s=0; dilate1(commit rows) re-eval after)
    if (s == 0) {
      for (int r = rlo + wv; r <= rhi; r += 4) {
        float a = xs[((r - 1) << 6) + ln];
        float b = xs[(r << 6) + ln];
        float c = xs[((r + 1) << 6) + ln];
        float vv = fmaxf(fmaxf(a, b), c);      // vertical max, own col
        float hl = __shfl(vv, ln - 1);         // junk at lane 0 (never valid)
        float hr = __shfl(vv, ln + 1);         // junk at lane 63 (never valid)
        float M = fmaxf(fmaxf(hl, vv), hr);
        bool flag = false;
        if ((colw >> ln) & 1ULL) {
          float xv = b;
          if (__fsub_rn(M, xv) > 0.05f) {      // pre-test: good<1 => ub <= M
            float g = good[(r0g + r) * WW + (c0g + ln)];
            if (__fsub_rn(__fmul_rn(M, g), xv) > 0.05f) flag = true;
          }
        }
        unsigned long long f = __ballot(flag) & colw;
        if (ln == 0) {
          fm[r] = f;
          if (f) atomicOr(&s_flr[r >> 5], 1u << (r & 31));
        }
      }
    } else {
      unsigned long long arows = dil1(crw_prev) & rowsrect;
      int idx = 0;
      unsigned long long mrows = arows;
      while (mrows) {
        int r = __builtin_ctzll(mrows); mrows &= mrows - 1;
        if (((idx++) & 3) != wv) continue;
        unsigned long long cn = 0ULL;
        if ((crw_prev >> (r - 1)) & 1ULL) cn |= cm[r - 1];
        if ((crw_prev >> r) & 1ULL) cn |= cm[r];
        if ((crw_prev >> (r + 1)) & 1ULL) cn |= cm[r + 1];
        unsigned long long d = dil1(cn) & colw;
        if (!d) continue;
        float a = xs[((r - 1) << 6) + ln];
        float b = xs[(r << 6) + ln];
        float c = xs[((r + 1) << 6) + ln];
        float vv = fmaxf(fmaxf(a, b), c);
        float hl = __shfl(vv, ln - 1);
        float hr = __shfl(vv, ln + 1);
        float M = fmaxf(fmaxf(hl, vv), hr);
        bool flag = false;
        if ((d >> ln) & 1ULL) {
          float xv = b;
          if (__fsub_rn(M, xv) > 0.05f) {
            float g = good[(r0g + r) * WW + (c0g + ln)];
            if (__fsub_rn(__fmul_rn(M, g), xv) > 0.05f) flag = true;
          }
        }
        unsigned long long f = (fm[r] & ~d) | (__ballot(flag) & d);
        if (ln == 0) {
          fm[r] = f;
          if (f) atomicOr(&s_flr[r >> 5], 1u << (r & 31));
          else   atomicAnd(&s_flr[r >> 5], ~(1u << (r & 31)));
        }
      }
    }
    __syncthreads();  // B1: fm/flagrows visible

    const unsigned long long flr =
        s_flr[0] | ((unsigned long long)s_flr[1] << 32);
    if (!(flr & rowsrect)) { broke = 1; break; }  // frozen => forever

    // ---- jitter frontier (rows in dilate1(flagrows)); clear commitrows
    if (tid < 2) s_crw[tid] = 0u;
    {
      unsigned long long jrows = dil1(flr) & rmask(rlo - 1, rhi + 1);
      int idx = 0;
      unsigned long long mrows = jrows;
      while (mrows) {
        int r = __builtin_ctzll(mrows); mrows &= mrows - 1;
        if (((idx++) & 3) != wv) continue;
        unsigned long long fu = 0ULL;
        if (r - 1 >= rlo && r - 1 <= rhi) fu |= fm[r - 1];
        if (r     >= rlo && r     <= rhi) fu |= fm[r];
        if (r + 1 >= rlo && r + 1 <= rhi) fu |= fm[r + 1];
        fu &= colw;
        if (!fu) continue;
        unsigned long long need = dil1(fu);
        if ((need >> ln) & 1ULL) {
          float xv = xs[(r << 6) + ln];
          float tv = 0.0f;
          if (xv != 0.0f) {                    // t = 0*s1 == +0 exactly
            int gr = r0g + r;  gr = gr < 0 ? 0 : (gr > HH - 1 ? HH - 1 : gr);
            int gc = c0g + ln; gc = gc < 0 ? 0 : (gc > WW - 1 ? WW - 1 : gc);
            float u = uniform01(kk.a0[s], kk.a1[s], (uint32_t)(gr * WW + gc));
            float s1 = __fadd_rn((float)(1.0 - 1e-4), __fmul_rn(1e-4f, u));
            tv = __fmul_rn(xv, s1);
          }
          ts[(r << 6) + ln] = tv;
        }
      }
    }
    __syncthreads();  // B2: ts visible, crw cleared

    // ---- pass B: exact maxpool(t) + coin + commit at flagged px
    {
      unsigned long long brows = flr & rowsrect;
      int idx = 0;
      unsigned long long mrows = brows;
      while (mrows) {
        int r = __builtin_ctzll(mrows); mrows &= mrows - 1;
        if (((idx++) & 3) != wv) continue;
        unsigned long long wf = fm[r] & colw;
        if (!wf) continue;
        // ts garbage only exists >1 lane away from any flag, never consumed
        float t0 = ts[((r - 1) << 6) + ln];
        float t1 = ts[(r << 6) + ln];
        float t2 = ts[((r + 1) << 6) + ln];
        float vt = fmaxf(fmaxf(t0, t1), t2);
        float hl = __shfl(vt, ln - 1);
        float hr = __shfl(vt, ln + 1);
        float m = fmaxf(fmaxf(hl, vt), hr);
        bool ok = false;
        float v = 0.0f;
        if ((wf >> ln) & 1ULL) {
          int gp = (r0g + r) * WW + (c0g + ln);  // in rect => in bounds
          float xv = xs[(r << 6) + ln];
          v = __fmul_rn(m, good[gp]);
          if (__fsub_rn(v, xv) > 0.05f) {      // exact test -> coin draw
            float u2 = uniform01(kk.b0[s], kk.b1[s], (uint32_t)gp);
            ok = (u2 > 0.5f);
          }
        }
        unsigned long long bal = __ballot(ok);
        if (ok) xs[(r << 6) + ln] = v;         // max(v,x)=v since v-x>THR>0
        if (bal && ln == 0) {
          cm[r] = bal;
          atomicOr(&s_crw[r >> 5], 1u << (r & 31));
        }
      }
    }
    __syncthreads();  // B3: commits/crw visible

    // ---- refresh dup ring for grid-edge tiles (only layer 15/48 is read)
    if (edge) {
      unsigned long long crw =
          s_crw[0] | ((unsigned long long)s_crw[1] << 32);
      if (crw) {  // no commits => xs unchanged => ring still valid
        if (top && tid < SD) xs[(15 << 6) + tid] = xs[(16 << 6) + tid];
        if (bot && tid < SD) xs[(48 << 6) + tid] = xs[(47 << 6) + tid];
        __syncthreads();
        if (lef && tid < SD) xs[(tid << 6) + 15] = xs[(tid << 6) + 16];
        if (rig && tid < SD) xs[(tid << 6) + 48] = xs[(tid << 6) + 47];
        __syncthreads();
      }
    }
  }

  if (tid == 0) st_out[tix] = broke ? 0 : 1;

  // ---- write back central 32x32 (float4; exit paths all end on a barrier)
  {
    int r = tid >> 3, c4 = tid & 7;            // 32 rows x 8 float4
    *(float4*)(xout + (r0b + r) * WW + c0b + 4 * c4) =
        *(const float4*)(xs + ((r + HALO) << 6) + HALO + 4 * c4);
  }
}

extern "C" void kernel_launch(void* const* d_in, const int* in_sizes, int n_in,
                              void* d_out, int out_size, void* d_ws, size_t ws_size,
                              hipStream_t stream) {
  const float* seed = (const float*)d_in[0];
  const float* hab  = (const float*)d_in[1];
  const float* good = (const float*)d_in[2];
  float* bufA = (float*)d_out;
  float* bufB = (float*)d_ws;
  unsigned char* stA = (unsigned char*)d_ws + (16u << 20);  // after bufB
  unsigned char* stB = stA + NTILE;

  // 7 fused launches (6x16 + 1x4): init -> bufB, odd count ends in bufA=d_out.
  k_init<<<dim3(NPIX / 256), dim3(256), 0, stream>>>(seed, hab, good, bufB, stA);

  // sum(delta)==0.0 exactly (required for early exit) is unreachable once any
  // seed is nonzero (coin toss gives delta = -x < 0 somewhere) -> all 100 steps.
  float* cur = bufB;
  unsigned char* stIn = stA; unsigned char* stOut = stB;
  dim3 grd(NB, NB), blk(256);
  for (int base = 0; base < 100; base += K_MAX) {
    Keys kk;
    kk.K = (100 - base < K_MAX) ? (100 - base) : K_MAX;
    for (int s = 0; s < kk.K; ++s) {
      uint32_t f0, f1;
      tf2x32(0u, 42u, 0u, (uint32_t)(base + s), &f0, &f1);  // fold_in(key, i)
      tf2x32(f0, f1, 0u, 0u, &kk.a0[s], &kk.a1[s]);         // split -> jitter
      tf2x32(f0, f1, 0u, 1u, &kk.b0[s], &kk.b1[s]);         // split -> coin
    }
    float* nxt = (cur == bufB) ? bufA : bufB;
    k_fused<<<grd, blk, 0, stream>>>(cur, good, nxt, stIn, stOut, kk);
    cur = nxt;
    unsigned char* t = stIn; stIn = stOut; stOut = t;
  }
  // cur == bufA == d_out (7 toggles from bufB)
}